// Round 14
// baseline (351.102 us; speedup 1.0000x reference)
//
#include <hip/hip_runtime.h>

using short8 = __attribute__((ext_vector_type(8))) short;
using h8     = __attribute__((ext_vector_type(8))) _Float16;
using h2     = __attribute__((ext_vector_type(2))) _Float16;
using f32x4  = __attribute__((ext_vector_type(4))) float;

#define NB  16
#define NTH 512
// ws layout (ushort units, all f16 bits)
#define WBIN_OFF 0         // [64 n][192 k]
#define WFIN_OFF 12288     // [160 n][64 k]
#define EMBO_OFF 22528     // [100 r][64 k]
#define LTAB_OFF 28928     // [6 p][100 v][64 n]
#define WS_USHORTS 67328
// probe scratch (ushort indices): head floats at byte off 8 MB, keepalive at 18 MB
#define SCR_HEAD_US 4194304
#define SCR_KEEP_US 9437184

__device__ __forceinline__ unsigned short f2h_bits(float v) {
    _Float16 h = (_Float16)v;
    return *reinterpret_cast<unsigned short*>(&h);
}
__device__ __forceinline__ h8 ld8h(const unsigned short* p) {
    return *reinterpret_cast<const h8*>(p);
}
__device__ __forceinline__ short8 ld8s(const unsigned short* p) {
    return *reinterpret_cast<const short8*>(p);
}
__device__ __forceinline__ f32x4 mf(h8 a, h8 b, f32x4 c) {
    return __builtin_amdgcn_mfma_f32_16x16x32_f16(a, b, c, 0, 0, 0);
}

// ---------------- prep: build f16 weights + leaf lookup tables --------------
__global__ void prep_kernel(const float* __restrict__ emb_pred,
                            const float* __restrict__ emb_var,
                            const float* __restrict__ emb_op,
                            const float* __restrict__ W_pred,
                            const float* __restrict__ W_bin,
                            const float* __restrict__ W_final,
                            unsigned short* __restrict__ ws) {
    for (int i = blockIdx.x * blockDim.x + threadIdx.x; i < WS_USHORTS;
         i += gridDim.x * blockDim.x) {
        float v = 0.f;
        if (i < WFIN_OFF) {
            int n = i / 192, k = i - n * 192, p = k >> 6, j = k & 63;
            if (n < 50 && j < 50) v = W_bin[n * 150 + p * 50 + j];
        } else if (i < EMBO_OFF) {
            int t = i - WFIN_OFF, o = t >> 6, k = t & 63;
            if (o < 155 && k < 50) v = W_final[o * 50 + k];
        } else if (i < LTAB_OFF) {
            int t = i - EMBO_OFF, r = t >> 6, j = t & 63;
            if (j < 50) v = emb_op[r * 50 + j];
        } else {
            int t = i - LTAB_OFF;
            int p = t / 6400, rest = t - p * 6400, vv = rest >> 6, n = rest & 63;
            if (n < 50) {
                const float* e = (p == 0) ? (emb_pred + vv * 50) : (emb_var + vv * 50);
                const float* wr = W_pred + n * 300 + p * 50;
                float acc = 0.f;
                for (int k = 0; k < 50; ++k) acc += e[k] * wr[k];
                v = acc;
            }
        }
        ws[i] = f2h_bits(v);
    }
}

// one tree node, compile-time N-tile subset [NT0, NT0+NTN)
#define TNODE(NT0, NTN, CL, CR, GN, DST) do {                                   \
    const unsigned short* rl_ = s_x[CL];                                        \
    const unsigned short* rr_ = s_x[CR];                                        \
    int r_ = s_op[(GN) * 16 + l15];                                             \
    h8 aL0 = ld8h(rl_ + l15 * 64 + ((quad ^ (l15 & 7)) << 3));                  \
    h8 aL1 = ld8h(rl_ + l15 * 64 + (((quad + 4) ^ (l15 & 7)) << 3));            \
    h8 aO0 = ld8h(s_embop + r_ * 64 + ((quad ^ (r_ & 7)) << 3));                \
    h8 aO1 = ld8h(s_embop + r_ * 64 + (((quad + 4) ^ (r_ & 7)) << 3));          \
    h8 aR0 = ld8h(rr_ + l15 * 64 + ((quad ^ (l15 & 7)) << 3));                  \
    h8 aR1 = ld8h(rr_ + l15 * 64 + (((quad + 4) ^ (l15 & 7)) << 3));            \
    f32x4 acc_[NTN];                                                            \
    _Pragma("unroll") for (int i_ = 0; i_ < (NTN); ++i_) {                      \
        acc_[i_] = (f32x4){0.f, 0.f, 0.f, 0.f};                                 \
        acc_[i_] = mf(aL0, wb[0][0][(NT0) + i_], acc_[i_]);                     \
        acc_[i_] = mf(aL1, wb[0][1][(NT0) + i_], acc_[i_]);                     \
        acc_[i_] = mf(aO0, wb[1][0][(NT0) + i_], acc_[i_]);                     \
        acc_[i_] = mf(aO1, wb[1][1][(NT0) + i_], acc_[i_]);                     \
        acc_[i_] = mf(aR0, wb[2][0][(NT0) + i_], acc_[i_]);                     \
        acc_[i_] = mf(aR1, wb[2][1][(NT0) + i_], acc_[i_]);                     \
    }                                                                           \
    unsigned short* drow_ = s_x[DST];                                           \
    _Pragma("unroll") for (int i_ = 0; i_ < (NTN); ++i_) {                      \
        int n_ = ((NT0) + i_) * 16 + l15;                                       \
        _Pragma("unroll") for (int q_ = 0; q_ < 4; ++q_) {                      \
            int m_ = quad * 4 + q_;                                             \
            float v_ = fmaxf(acc_[i_][q_] + biasb[(NT0) + i_], 0.f);            \
            drow_[m_ * 64 + (((n_ >> 3) ^ (m_ & 7)) << 3) + (n_ & 7)] = f2h_bits(v_); \
        }                                                                       \
    }                                                                           \
} while (0)

// ---------------- main kernel, phase-selectable -----------------------------
// MODE bits: 1=leaf, 2=tree, 4=head, 16=lane-uniform leaf rows (TA-minimal).
// MODE==7 is the production R10 kernel (writes out). Probe modes write only
// ws scratch. REP repeats the selected phases.
template<int MODE, int REP>
__global__ __launch_bounds__(NTH, 2) void formula_kernel(
    const int* __restrict__ pred_ids, const int* __restrict__ arg_ids,
    const int* __restrict__ op_ids,
    const float* __restrict__ b_pred, const float* __restrict__ b_bin,
    const float* __restrict__ b_final,
    const unsigned short* __restrict__ ws,
    float* __restrict__ out, unsigned short* __restrict__ wss)
{
    __shared__ __align__(16) unsigned short s_x[64][1024];         // 131072 B
    __shared__ __align__(16) unsigned short s_embop[100 * 64];     //  12800 B
    __shared__ __align__(8)  unsigned char  s_ids[64][16][8];      //   8192 B
    __shared__ unsigned char s_op[63 * 16 + 16];                   //   1024 B

    const int tid  = threadIdx.x;
    const int b0   = blockIdx.x * NB;
    const int lane = tid & 63;
    const int w    = tid >> 6;
    const int l15  = lane & 15;
    const int quad = lane >> 4;
    const int cg   = tid & 7;

    float* hout = (MODE == 7) ? out
                : reinterpret_cast<float*>(wss + SCR_HEAD_US);

    // ---- stage (identical to R10) ----
    for (int i = tid; i < 800; i += NTH) {
        int r = i >> 3, s = i & 7;
        *reinterpret_cast<short8*>(&s_embop[r * 64 + ((s ^ (r & 7)) << 3)]) =
            ld8s(ws + EMBO_OFF + r * 64 + s * 8);
    }
    for (int e = tid; e < 64 * 16; e += NTH) {
        int m = e >> 6, lf = e & 63;
        unsigned char* rec = &s_ids[lf][m][0];
        rec[0] = (unsigned char)pred_ids[(b0 + m) * 64 + lf];
        #pragma unroll
        for (int a = 0; a < 5; ++a)
            rec[1 + a] = (unsigned char)arg_ids[(b0 + m) * 320 + lf * 5 + a];
        rec[6] = 0; rec[7] = 0;
    }
    for (int e = tid; e < 63 * 16; e += NTH) {
        int r = e >> 4, m = e & 15;
        s_op[r * 16 + m] = (unsigned char)op_ids[(b0 + m) * 63 + r];
    }

    short8 wb_raw[3][2][4];
    #pragma unroll
    for (int p = 0; p < 3; ++p)
        #pragma unroll
        for (int h = 0; h < 2; ++h)
            #pragma unroll
            for (int nt = 0; nt < 4; ++nt)
                wb_raw[p][h][nt] = ld8s(ws + WBIN_OFF + (nt * 16 + l15) * 192
                                        + p * 64 + (quad + 4 * h) * 8);
    h8 (&wb)[3][2][4] = reinterpret_cast<h8(&)[3][2][4]>(wb_raw);

    float biasb[4];
    #pragma unroll
    for (int nt = 0; nt < 4; ++nt) {
        int n = nt * 16 + l15;
        biasb[nt] = (n < 50) ? b_bin[n] : 0.f;
    }
    h2 bias2[4];
    #pragma unroll
    for (int k = 0; k < 4; ++k) {
        int n0 = cg * 8 + 2 * k, n1 = n0 + 1;
        bias2[k] = (h2){(_Float16)((n0 < 50) ? b_pred[n0] : 0.f),
                        (_Float16)((n1 < 50) ? b_pred[n1] : 0.f)};
    }
    const h2 z2 = (h2){(_Float16)0.f, (_Float16)0.f};

    __syncthreads();

    #pragma unroll 1
    for (int rep = 0; rep < REP; ++rep) {
        if constexpr (MODE & 1) {
            // ---- leaf layer: 8192 jobs, 16/thread ----
            #pragma unroll 4
            for (int p4 = 0; p4 < 16; ++p4) {
                int jj  = p4 * NTH + tid;
                int lf  = jj >> 7;
                int m   = (jj >> 3) & 15;
                const unsigned int* ivp =
                    reinterpret_cast<const unsigned int*>(&s_ids[lf][m][0]);
                unsigned int ix = ivp[0], iy = ivp[1];
                int r0, r1, r2, r3, r4, r5;
                if constexpr (MODE & 16) {
                    int rr = (p4 * 8 + rep) & 63;   // lane-uniform, loop-variant
                    r0 = r1 = r2 = r3 = r4 = r5 = rr;
                } else {
                    r0 = ix & 255; r1 = (ix >> 8) & 255; r2 = (ix >> 16) & 255;
                    r3 = ix >> 24; r4 = iy & 255; r5 = (iy >> 8) & 255;
                }
                h2 a0 = bias2[0], a1 = bias2[1], a2 = bias2[2], a3 = bias2[3];
                #define ACCT(ROW, P) {                                          \
                    h8 t_ = ld8h(ws + LTAB_OFF + (P) * 6400 + (ROW) * 64 + cg * 8); \
                    const h2* tp_ = reinterpret_cast<const h2*>(&t_);           \
                    a0 += tp_[0]; a1 += tp_[1]; a2 += tp_[2]; a3 += tp_[3]; }
                ACCT(r0, 0); ACCT(r1, 1); ACCT(r2, 2);
                ACCT(r3, 3); ACCT(r4, 4); ACCT(r5, 5);
                #undef ACCT
                a0 = __builtin_elementwise_max(a0, z2);
                a1 = __builtin_elementwise_max(a1, z2);
                a2 = __builtin_elementwise_max(a2, z2);
                a3 = __builtin_elementwise_max(a3, z2);
                union { h2 h[4]; short8 s; } u;
                u.h[0] = a0; u.h[1] = a1; u.h[2] = a2; u.h[3] = a3;
                *reinterpret_cast<short8*>(
                    &s_x[lf][m * 64 + ((cg ^ (m & 7)) << 3)]) = u.s;
            }
        }
        __syncthreads();

        if constexpr (MODE & 2) {
            #pragma unroll
            for (int i = 0; i < 4; ++i) {
                int j = w + 8 * i;
                TNODE(0, 4, 2 * j, 2 * j + 1, j, 2 * j);
            }
            __syncthreads();
            #pragma unroll
            for (int i = 0; i < 2; ++i) {
                int j = w + 8 * i;
                TNODE(0, 4, 4 * j, 4 * j + 2, 32 + j, 4 * j);
            }
            __syncthreads();
            { int j = w; TNODE(0, 4, 8 * j, 8 * j + 4, 48 + j, 8 * j); }
            __syncthreads();
            {
                int j = w >> 1;
                if ((w & 1) == 0) TNODE(0, 2, 16 * j, 16 * j + 8, 56 + j, 16 * j + 1);
                else              TNODE(2, 2, 16 * j, 16 * j + 8, 56 + j, 16 * j + 1);
            }
            __syncthreads();
            {
                int j = w >> 2;
                switch (w & 3) {
                    case 0: TNODE(0, 1, 32 * j + 1, 32 * j + 17, 60 + j, 32 * j + 2); break;
                    case 1: TNODE(1, 1, 32 * j + 1, 32 * j + 17, 60 + j, 32 * j + 2); break;
                    case 2: TNODE(2, 1, 32 * j + 1, 32 * j + 17, 60 + j, 32 * j + 2); break;
                    default: TNODE(3, 1, 32 * j + 1, 32 * j + 17, 60 + j, 32 * j + 2); break;
                }
            }
            __syncthreads();
            if (w < 4) {
                switch (w) {
                    case 0: TNODE(0, 1, 2, 34, 62, 1); break;
                    case 1: TNODE(1, 1, 2, 34, 62, 1); break;
                    case 2: TNODE(2, 1, 2, 34, 62, 1); break;
                    default: TNODE(3, 1, 2, 34, 62, 1); break;
                }
            }
        }
        __syncthreads();

        if constexpr (MODE & 4) {
            auto headtile = [&](int t) {
                f32x4 acc = {0.f, 0.f, 0.f, 0.f};
                int n2 = t * 16 + l15;
                const unsigned short* rroot = s_x[1];
                h8 x0 = ld8h(rroot + l15 * 64 + ((quad ^ (l15 & 7)) << 3));
                h8 x1 = ld8h(rroot + l15 * 64 + (((quad + 4) ^ (l15 & 7)) << 3));
                acc = mf(x0, ld8h(ws + WFIN_OFF + n2 * 64 + quad * 8), acc);
                acc = mf(x1, ld8h(ws + WFIN_OFF + n2 * 64 + (quad + 4) * 8), acc);
                if (n2 < 155) {
                    float bias = b_final[n2];
                    #pragma unroll
                    for (int q = 0; q < 4; ++q) {
                        int m = quad * 4 + q;
                        hout[(b0 + m) * 155 + n2] = acc[q] + bias;
                    }
                }
            };
            headtile(w);
            if (w < 2) headtile(8 + w);
        }
        __syncthreads();
    }

    // keep-alive for probe modes (prevents any whole-phase DCE)
    if constexpr (MODE != 7) {
        if (tid == 0) wss[SCR_KEEP_US + blockIdx.x] = s_x[1][0];
    }
}

extern "C" void kernel_launch(void* const* d_in, const int* in_sizes, int n_in,
                              void* d_out, int out_size, void* d_ws, size_t ws_size,
                              hipStream_t stream) {
    const int*   pred_ids = (const int*)  d_in[0];
    const int*   arg_ids  = (const int*)  d_in[1];
    const int*   op_ids   = (const int*)  d_in[2];
    const float* emb_pred = (const float*)d_in[3];
    const float* emb_var  = (const float*)d_in[4];
    const float* emb_op   = (const float*)d_in[5];
    const float* W_pred   = (const float*)d_in[6];
    const float* b_pred   = (const float*)d_in[7];
    const float* W_bin    = (const float*)d_in[8];
    const float* b_bin    = (const float*)d_in[9];
    const float* W_final  = (const float*)d_in[10];
    const float* b_final  = (const float*)d_in[11];
    unsigned short* ws = (unsigned short*)d_ws;
    float* out = (float*)d_out;

    hipLaunchKernelGGL(prep_kernel, dim3(256), dim3(256), 0, stream,
                       emb_pred, emb_var, emb_op, W_pred, W_bin, W_final, ws);
    // V0: production (writes out)
    hipLaunchKernelGGL((formula_kernel<7, 1>), dim3(4096 / NB), dim3(NTH), 0, stream,
                       pred_ids, arg_ids, op_ids, b_pred, b_bin, b_final,
                       (const unsigned short*)ws, out, ws);
    // probes: phase isolation (write only deep ws scratch)
    hipLaunchKernelGGL((formula_kernel<1, 8>), dim3(4096 / NB), dim3(NTH), 0, stream,
                       pred_ids, arg_ids, op_ids, b_pred, b_bin, b_final,
                       (const unsigned short*)ws, out, ws);
    hipLaunchKernelGGL((formula_kernel<17, 24>), dim3(4096 / NB), dim3(NTH), 0, stream,
                       pred_ids, arg_ids, op_ids, b_pred, b_bin, b_final,
                       (const unsigned short*)ws, out, ws);
    hipLaunchKernelGGL((formula_kernel<2, 8>), dim3(4096 / NB), dim3(NTH), 0, stream,
                       pred_ids, arg_ids, op_ids, b_pred, b_bin, b_final,
                       (const unsigned short*)ws, out, ws);
    hipLaunchKernelGGL((formula_kernel<4, 64>), dim3(4096 / NB), dim3(NTH), 0, stream,
                       pred_ids, arg_ids, op_ids, b_pred, b_bin, b_final,
                       (const unsigned short*)ws, out, ws);
}

// Round 15
// 39.815 us; speedup vs baseline: 8.8184x; 8.8184x over previous
//
#include <hip/hip_runtime.h>

using short8 = __attribute__((ext_vector_type(8))) short;
using h8     = __attribute__((ext_vector_type(8))) _Float16;
using h2     = __attribute__((ext_vector_type(2))) _Float16;
using f32x4  = __attribute__((ext_vector_type(4))) float;

#define NB  16
#define NTH 512
// ws layout (ushort units, all f16 bits)
#define WBIN_OFF 0         // [64 n][192 k]
#define WFIN_OFF 12288     // [160 n][64 k]
#define EMBO_OFF 22528     // [100 r][64 k] linear (read from global in tree)
#define LTAB_OFF 28928     // [6 p][100 v][64 n]
#define WS_USHORTS 67328

__device__ __forceinline__ unsigned short f2h_bits(float v) {
    _Float16 h = (_Float16)v;
    return *reinterpret_cast<unsigned short*>(&h);
}
__device__ __forceinline__ h8 ld8h(const unsigned short* p) {
    return *reinterpret_cast<const h8*>(p);
}
__device__ __forceinline__ short8 ld8s(const unsigned short* p) {
    return *reinterpret_cast<const short8*>(p);
}
__device__ __forceinline__ f32x4 mf(h8 a, h8 b, f32x4 c) {
    return __builtin_amdgcn_mfma_f32_16x16x32_f16(a, b, c, 0, 0, 0);
}

// ---------------- prep: build f16 weights + leaf lookup tables --------------
__global__ void prep_kernel(const float* __restrict__ emb_pred,
                            const float* __restrict__ emb_var,
                            const float* __restrict__ emb_op,
                            const float* __restrict__ W_pred,
                            const float* __restrict__ W_bin,
                            const float* __restrict__ W_final,
                            unsigned short* __restrict__ ws) {
    for (int i = blockIdx.x * blockDim.x + threadIdx.x; i < WS_USHORTS;
         i += gridDim.x * blockDim.x) {
        float v = 0.f;
        if (i < WFIN_OFF) {                      // W_bin [64][192]
            int n = i / 192, k = i - n * 192, p = k >> 6, j = k & 63;
            if (n < 50 && j < 50) v = W_bin[n * 150 + p * 50 + j];
        } else if (i < EMBO_OFF) {               // W_final [160][64]
            int t = i - WFIN_OFF, o = t >> 6, k = t & 63;
            if (o < 155 && k < 50) v = W_final[o * 50 + k];
        } else if (i < LTAB_OFF) {               // emb_op [100][64]
            int t = i - EMBO_OFF, r = t >> 6, j = t & 63;
            if (j < 50) v = emb_op[r * 50 + j];
        } else {                                 // leaf tables [6][100][64]
            int t = i - LTAB_OFF;
            int p = t / 6400, rest = t - p * 6400, vv = rest >> 6, n = rest & 63;
            if (n < 50) {
                const float* e = (p == 0) ? (emb_pred + vv * 50) : (emb_var + vv * 50);
                const float* wr = W_pred + n * 300 + p * 50;
                float acc = 0.f;
                for (int k = 0; k < 50; ++k) acc += e[k] * wr[k];
                v = acc;
            }
        }
        ws[i] = f2h_bits(v);
    }
}

// one tree node, compile-time N-tile subset [NT0, NT0+NTN)
// op-embedding fragments from GLOBAL ws (tree phase is cheap per R14 ablation)
#define TNODE(NT0, NTN, CL, CR, GN, DST) do {                                   \
    const unsigned short* rl_ = s_x[CL];                                        \
    const unsigned short* rr_ = s_x[CR];                                        \
    int r_ = s_op[(GN) * 16 + l15];                                             \
    h8 aL0 = ld8h(rl_ + l15 * 64 + ((quad ^ (l15 & 7)) << 3));                  \
    h8 aL1 = ld8h(rl_ + l15 * 64 + (((quad + 4) ^ (l15 & 7)) << 3));            \
    h8 aO0 = ld8h(ws + EMBO_OFF + r_ * 64 + quad * 8);                          \
    h8 aO1 = ld8h(ws + EMBO_OFF + r_ * 64 + (quad + 4) * 8);                    \
    h8 aR0 = ld8h(rr_ + l15 * 64 + ((quad ^ (l15 & 7)) << 3));                  \
    h8 aR1 = ld8h(rr_ + l15 * 64 + (((quad + 4) ^ (l15 & 7)) << 3));            \
    f32x4 acc_[NTN];                                                            \
    _Pragma("unroll") for (int i_ = 0; i_ < (NTN); ++i_) {                      \
        acc_[i_] = (f32x4){0.f, 0.f, 0.f, 0.f};                                 \
        acc_[i_] = mf(aL0, wb[0][0][(NT0) + i_], acc_[i_]);                     \
        acc_[i_] = mf(aL1, wb[0][1][(NT0) + i_], acc_[i_]);                     \
        acc_[i_] = mf(aO0, wb[1][0][(NT0) + i_], acc_[i_]);                     \
        acc_[i_] = mf(aO1, wb[1][1][(NT0) + i_], acc_[i_]);                     \
        acc_[i_] = mf(aR0, wb[2][0][(NT0) + i_], acc_[i_]);                     \
        acc_[i_] = mf(aR1, wb[2][1][(NT0) + i_], acc_[i_]);                     \
    }                                                                           \
    unsigned short* drow_ = s_x[DST];                                           \
    _Pragma("unroll") for (int i_ = 0; i_ < (NTN); ++i_) {                      \
        int n_ = ((NT0) + i_) * 16 + l15;                                       \
        _Pragma("unroll") for (int q_ = 0; q_ < 4; ++q_) {                      \
            int m_ = quad * 4 + q_;                                             \
            float v_ = fmaxf(acc_[i_][q_] + biasb[(NT0) + i_], 0.f);            \
            drow_[m_ * 64 + (((n_ >> 3) ^ (m_ & 7)) << 3) + (n_ & 7)] = f2h_bits(v_); \
        }                                                                       \
    }                                                                           \
} while (0)

// ---------------- main fused kernel -----------------------------------------
// R14 ablation: leaf random-gather = 19.4 us/pass (~75% of kernel), >=3x from
// address divergence (L1-thrash). Fix: leaf tables in LDS (divergence-immune,
// 128 B/cy structural). Paid by 2-chunk subtree schedule: 32 leaves/chunk,
// s_x 35 rows. LDS: ltab 76800 + s_x 71680 + ids 8192 + op 1024 = 157696 B.
// Per-chunk row map (rows 0..31 leaf, reused per chunk):
//   lev0 j(16,2/wave): rd 2j,2j+1 -> 2j (in-place) | lev1 j(8,1/wave):
//   rd 4j,4j+2 -> 4j | lev2 j(4,2 waves): rd 8j,8j+4 -> 8j+1 (dead) |
//   lev3 j(2,4 waves): rd 16j+1,16j+9 -> 16j+2 (dead) | lev4 (4 waves):
//   rd 2,18 -> 32+c | root: rd 32,33 -> 34 | head reads 34.
__global__ __launch_bounds__(NTH, 2) void formula_kernel(
    const int* __restrict__ pred_ids, const int* __restrict__ arg_ids,
    const int* __restrict__ op_ids,
    const float* __restrict__ b_pred, const float* __restrict__ b_bin,
    const float* __restrict__ b_final,
    const unsigned short* __restrict__ ws,
    float* __restrict__ out)
{
    __shared__ __align__(16) unsigned short s_ltab[6 * 100 * 64];  // 76800 B
    __shared__ __align__(16) unsigned short s_x[35][1024];         // 71680 B
    __shared__ __align__(8)  unsigned char  s_ids[64][16][8];      //  8192 B
    __shared__ unsigned char s_op[63 * 16 + 16];                   //  1024 B

    const int tid  = threadIdx.x;
    const int b0   = blockIdx.x * NB;
    const int lane = tid & 63;
    const int w    = tid >> 6;       // wave 0..7
    const int l15  = lane & 15;
    const int quad = lane >> 4;
    const int cg   = tid & 7;        // constant col-group (leaf phase)

    // ---- stage leaf tables into LDS (linear; 4800 short8 groups) ----
    for (int i = tid; i < 4800; i += NTH)
        *reinterpret_cast<short8*>(&s_ltab[i * 8]) = ld8s(ws + LTAB_OFF + i * 8);
    // ---- stage ids: s_ids[leaf][m] = {pred, a0..a4, 0, 0} ----
    for (int e = tid; e < 64 * 16; e += NTH) {
        int m = e >> 6, lf = e & 63;
        unsigned char* rec = &s_ids[lf][m][0];
        rec[0] = (unsigned char)pred_ids[(b0 + m) * 64 + lf];
        #pragma unroll
        for (int a = 0; a < 5; ++a)
            rec[1 + a] = (unsigned char)arg_ids[(b0 + m) * 320 + lf * 5 + a];
        rec[6] = 0; rec[7] = 0;
    }
    for (int e = tid; e < 63 * 16; e += NTH) {
        int r = e >> 4, m = e & 15;
        s_op[r * 16 + m] = (unsigned char)op_ids[(b0 + m) * 63 + r];
    }

    // ---- persistent W_bin fragments: all 4 N-tiles in regs (24 VGPR) ----
    short8 wb_raw[3][2][4];
    #pragma unroll
    for (int p = 0; p < 3; ++p)
        #pragma unroll
        for (int h = 0; h < 2; ++h)
            #pragma unroll
            for (int nt = 0; nt < 4; ++nt)
                wb_raw[p][h][nt] = ld8s(ws + WBIN_OFF + (nt * 16 + l15) * 192
                                        + p * 64 + (quad + 4 * h) * 8);
    h8 (&wb)[3][2][4] = reinterpret_cast<h8(&)[3][2][4]>(wb_raw);

    float biasb[4];
    #pragma unroll
    for (int nt = 0; nt < 4; ++nt) {
        int n = nt * 16 + l15;
        biasb[nt] = (n < 50) ? b_bin[n] : 0.f;
    }
    h2 bias2[4];
    #pragma unroll
    for (int k = 0; k < 4; ++k) {
        int n0 = cg * 8 + 2 * k, n1 = n0 + 1;
        bias2[k] = (h2){(_Float16)((n0 < 50) ? b_pred[n0] : 0.f),
                        (_Float16)((n1 < 50) ? b_pred[n1] : 0.f)};
    }
    const h2 z2 = (h2){(_Float16)0.f, (_Float16)0.f};

    __syncthreads();

    for (int c = 0; c < 2; ++c) {
        // ---- leaf layer: 32 leaves x 16 m x 8 cg = 4096 jobs, 8/thread,
        //      6 LDS-table gathers each (bank-balanced: full 128 B/cy) ----
        #pragma unroll 4
        for (int p4 = 0; p4 < 8; ++p4) {
            int jj  = p4 * NTH + tid;          // 0..4095
            int lfl = jj >> 7;                 // 0..31
            int m   = (jj >> 3) & 15;
            const unsigned int* ivp =
                reinterpret_cast<const unsigned int*>(&s_ids[c * 32 + lfl][m][0]);
            unsigned int ix = ivp[0], iy = ivp[1];
            int r0 = ix & 255, r1 = (ix >> 8) & 255, r2 = (ix >> 16) & 255;
            int r3 = ix >> 24, r4 = iy & 255, r5 = (iy >> 8) & 255;
            h2 a0 = bias2[0], a1 = bias2[1], a2 = bias2[2], a3 = bias2[3];
            #define ACCT(ROW, P) {                                              \
                h8 t_ = ld8h(s_ltab + (P) * 6400 + (ROW) * 64 + cg * 8);        \
                const h2* tp_ = reinterpret_cast<const h2*>(&t_);               \
                a0 += tp_[0]; a1 += tp_[1]; a2 += tp_[2]; a3 += tp_[3]; }
            ACCT(r0, 0); ACCT(r1, 1); ACCT(r2, 2);
            ACCT(r3, 3); ACCT(r4, 4); ACCT(r5, 5);
            #undef ACCT
            a0 = __builtin_elementwise_max(a0, z2);
            a1 = __builtin_elementwise_max(a1, z2);
            a2 = __builtin_elementwise_max(a2, z2);
            a3 = __builtin_elementwise_max(a3, z2);
            union { h2 h[4]; short8 s; } u;
            u.h[0] = a0; u.h[1] = a1; u.h[2] = a2; u.h[3] = a3;
            *reinterpret_cast<short8*>(
                &s_x[lfl][m * 64 + ((cg ^ (m & 7)) << 3)]) = u.s;
        }
        __syncthreads();

        // ---- lev0: 16 nodes, 2/wave (in-place) ----
        #pragma unroll
        for (int i = 0; i < 2; ++i) {
            int j = w + 8 * i;
            TNODE(0, 4, 2 * j, 2 * j + 1, c * 16 + j, 2 * j);
        }
        __syncthreads();
        // ---- lev1: 8 nodes, 1/wave (in-place) ----
        { int j = w; TNODE(0, 4, 4 * j, 4 * j + 2, 32 + c * 8 + j, 4 * j); }
        __syncthreads();
        // ---- lev2: 4 nodes x 2 waves -> dead row 8j+1 ----
        {
            int j = w >> 1;
            if ((w & 1) == 0) TNODE(0, 2, 8 * j, 8 * j + 4, 48 + c * 4 + j, 8 * j + 1);
            else              TNODE(2, 2, 8 * j, 8 * j + 4, 48 + c * 4 + j, 8 * j + 1);
        }
        __syncthreads();
        // ---- lev3: 2 nodes x 4 waves -> dead row 16j+2 ----
        {
            int j = w >> 2;
            switch (w & 3) {
                case 0: TNODE(0, 1, 16 * j + 1, 16 * j + 9, 56 + c * 2 + j, 16 * j + 2); break;
                case 1: TNODE(1, 1, 16 * j + 1, 16 * j + 9, 56 + c * 2 + j, 16 * j + 2); break;
                case 2: TNODE(2, 1, 16 * j + 1, 16 * j + 9, 56 + c * 2 + j, 16 * j + 2); break;
                default: TNODE(3, 1, 16 * j + 1, 16 * j + 9, 56 + c * 2 + j, 16 * j + 2); break;
            }
        }
        __syncthreads();
        // ---- lev4 (subtree root, waves 0..3): rd 2,18 -> 32+c ----
        if (w < 4) {
            switch (w) {
                case 0: TNODE(0, 1, 2, 18, 60 + c, 32 + c); break;
                case 1: TNODE(1, 1, 2, 18, 60 + c, 32 + c); break;
                case 2: TNODE(2, 1, 2, 18, 60 + c, 32 + c); break;
                default: TNODE(3, 1, 2, 18, 60 + c, 32 + c); break;
            }
        }
        __syncthreads();
    }
    // ---- root (waves 0..3): rd 32,33 -> 34 ----
    if (w < 4) {
        switch (w) {
            case 0: TNODE(0, 1, 32, 33, 62, 34); break;
            case 1: TNODE(1, 1, 32, 33, 62, 34); break;
            case 2: TNODE(2, 1, 32, 33, 62, 34); break;
            default: TNODE(3, 1, 32, 33, 62, 34); break;
        }
    }
    __syncthreads();

    // ---- final head via MFMA: 10 N-tiles over 8 waves (root = row 34) ----
    auto headtile = [&](int t) {
        f32x4 acc = {0.f, 0.f, 0.f, 0.f};
        int n2 = t * 16 + l15;
        const unsigned short* rroot = s_x[34];
        h8 x0 = ld8h(rroot + l15 * 64 + ((quad ^ (l15 & 7)) << 3));
        h8 x1 = ld8h(rroot + l15 * 64 + (((quad + 4) ^ (l15 & 7)) << 3));
        acc = mf(x0, ld8h(ws + WFIN_OFF + n2 * 64 + quad * 8), acc);
        acc = mf(x1, ld8h(ws + WFIN_OFF + n2 * 64 + (quad + 4) * 8), acc);
        if (n2 < 155) {
            float bias = b_final[n2];
            #pragma unroll
            for (int q = 0; q < 4; ++q) {
                int m = quad * 4 + q;
                out[(b0 + m) * 155 + n2] = acc[q] + bias;
            }
        }
    };
    headtile(w);
    if (w < 2) headtile(8 + w);
}

extern "C" void kernel_launch(void* const* d_in, const int* in_sizes, int n_in,
                              void* d_out, int out_size, void* d_ws, size_t ws_size,
                              hipStream_t stream) {
    const int*   pred_ids = (const int*)  d_in[0];
    const int*   arg_ids  = (const int*)  d_in[1];
    const int*   op_ids   = (const int*)  d_in[2];
    const float* emb_pred = (const float*)d_in[3];
    const float* emb_var  = (const float*)d_in[4];
    const float* emb_op   = (const float*)d_in[5];
    const float* W_pred   = (const float*)d_in[6];
    const float* b_pred   = (const float*)d_in[7];
    const float* W_bin    = (const float*)d_in[8];
    const float* b_bin    = (const float*)d_in[9];
    const float* W_final  = (const float*)d_in[10];
    const float* b_final  = (const float*)d_in[11];
    unsigned short* ws = (unsigned short*)d_ws;
    float* out = (float*)d_out;

    hipLaunchKernelGGL(prep_kernel, dim3(256), dim3(256), 0, stream,
                       emb_pred, emb_var, emb_op, W_pred, W_bin, W_final, ws);
    hipLaunchKernelGGL(formula_kernel, dim3(4096 / NB), dim3(NTH), 0, stream,
                       pred_ids, arg_ids, op_ids, b_pred, b_bin, b_final,
                       (const unsigned short*)ws, out);
}

// Round 16
// 38.909 us; speedup vs baseline: 9.0238x; 1.0233x over previous
//
#include <hip/hip_runtime.h>

using short8 = __attribute__((ext_vector_type(8))) short;
using h8     = __attribute__((ext_vector_type(8))) _Float16;
using h2     = __attribute__((ext_vector_type(2))) _Float16;
using f32x4  = __attribute__((ext_vector_type(4))) float;

#define NB  16
#define NTH 512
// ws layout (ushort units, all f16 bits)
#define WBIN_OFF 0         // [64 n][192 k]
#define WFIN_OFF 12288     // [160 n][64 k]
#define EMBO_OFF 22528     // [100 r][64 k]
#define LTAB_OFF 28928     // [6 p][100 v][64 n]
#define WS_USHORTS 67328

__device__ __forceinline__ unsigned short f2h_bits(float v) {
    _Float16 h = (_Float16)v;
    return *reinterpret_cast<unsigned short*>(&h);
}
__device__ __forceinline__ h8 ld8h(const unsigned short* p) {
    return *reinterpret_cast<const h8*>(p);
}
__device__ __forceinline__ short8 ld8s(const unsigned short* p) {
    return *reinterpret_cast<const short8*>(p);
}
__device__ __forceinline__ f32x4 mf(h8 a, h8 b, f32x4 c) {
    return __builtin_amdgcn_mfma_f32_16x16x32_f16(a, b, c, 0, 0, 0);
}

// ---------------- prep: build f16 weights + leaf lookup tables --------------
__global__ void prep_kernel(const float* __restrict__ emb_pred,
                            const float* __restrict__ emb_var,
                            const float* __restrict__ emb_op,
                            const float* __restrict__ W_pred,
                            const float* __restrict__ W_bin,
                            const float* __restrict__ W_final,
                            unsigned short* __restrict__ ws) {
    for (int i = blockIdx.x * blockDim.x + threadIdx.x; i < WS_USHORTS;
         i += gridDim.x * blockDim.x) {
        float v = 0.f;
        if (i < WFIN_OFF) {                      // W_bin [64][192]
            int n = i / 192, k = i - n * 192, p = k >> 6, j = k & 63;
            if (n < 50 && j < 50) v = W_bin[n * 150 + p * 50 + j];
        } else if (i < EMBO_OFF) {               // W_final [160][64]
            int t = i - WFIN_OFF, o = t >> 6, k = t & 63;
            if (o < 155 && k < 50) v = W_final[o * 50 + k];
        } else if (i < LTAB_OFF) {               // emb_op [100][64]
            int t = i - EMBO_OFF, r = t >> 6, j = t & 63;
            if (j < 50) v = emb_op[r * 50 + j];
        } else {                                 // leaf tables [6][100][64]
            int t = i - LTAB_OFF;
            int p = t / 6400, rest = t - p * 6400, vv = rest >> 6, n = rest & 63;
            if (n < 50) {
                const float* e = (p == 0) ? (emb_pred + vv * 50) : (emb_var + vv * 50);
                const float* wr = W_pred + n * 300 + p * 50;
                float acc = 0.f;
                for (int k = 0; k < 50; ++k) acc += e[k] * wr[k];
                v = acc;
            }
        }
        ws[i] = f2h_bits(v);
    }
}

// one tree node, compile-time N-tile subset [NT0, NT0+NTN)
// op embeddings from LDS (swizzled by r&7) — R10's layout
#define TNODE(NT0, NTN, CL, CR, GN, DST) do {                                   \
    const unsigned short* rl_ = s_x[CL];                                        \
    const unsigned short* rr_ = s_x[CR];                                        \
    int r_ = s_op[(GN) * 16 + l15];                                             \
    h8 aL0 = ld8h(rl_ + l15 * 64 + ((quad ^ (l15 & 7)) << 3));                  \
    h8 aL1 = ld8h(rl_ + l15 * 64 + (((quad + 4) ^ (l15 & 7)) << 3));            \
    h8 aO0 = ld8h(s_embop + r_ * 64 + ((quad ^ (r_ & 7)) << 3));                \
    h8 aO1 = ld8h(s_embop + r_ * 64 + (((quad + 4) ^ (r_ & 7)) << 3));          \
    h8 aR0 = ld8h(rr_ + l15 * 64 + ((quad ^ (l15 & 7)) << 3));                  \
    h8 aR1 = ld8h(rr_ + l15 * 64 + (((quad + 4) ^ (l15 & 7)) << 3));            \
    f32x4 acc_[NTN];                                                            \
    _Pragma("unroll") for (int i_ = 0; i_ < (NTN); ++i_) {                      \
        acc_[i_] = (f32x4){0.f, 0.f, 0.f, 0.f};                                 \
        acc_[i_] = mf(aL0, wb[0][0][(NT0) + i_], acc_[i_]);                     \
        acc_[i_] = mf(aL1, wb[0][1][(NT0) + i_], acc_[i_]);                     \
        acc_[i_] = mf(aO0, wb[1][0][(NT0) + i_], acc_[i_]);                     \
        acc_[i_] = mf(aO1, wb[1][1][(NT0) + i_], acc_[i_]);                     \
        acc_[i_] = mf(aR0, wb[2][0][(NT0) + i_], acc_[i_]);                     \
        acc_[i_] = mf(aR1, wb[2][1][(NT0) + i_], acc_[i_]);                     \
    }                                                                           \
    unsigned short* drow_ = s_x[DST];                                           \
    _Pragma("unroll") for (int i_ = 0; i_ < (NTN); ++i_) {                      \
        int n_ = ((NT0) + i_) * 16 + l15;                                       \
        _Pragma("unroll") for (int q_ = 0; q_ < 4; ++q_) {                      \
            int m_ = quad * 4 + q_;                                             \
            float v_ = fmaxf(acc_[i_][q_] + biasb[(NT0) + i_], 0.f);            \
            drow_[m_ * 64 + (((n_ >> 3) ^ (m_ & 7)) << 3) + (n_ & 7)] = f2h_bits(v_); \
        }                                                                       \
    }                                                                           \
} while (0)

// ---------------- main fused kernel -----------------------------------------
// R15 unbundled: BOTH random-access tables in LDS (ltab 76.8K + embop 12.8K),
// s_x 34 rows (69.6K), s_op 1K = 160256 B. ids read from global (s_ids dropped).
// 2-chunk schedule, per-chunk row map (rows 0..31 leaves):
//   lev0 j(16,2/wave): rd 2j,2j+1 -> 2j | lev1 j(8,1/wave): rd 4j,4j+2 -> 4j
//   lev2 j(4,2 waves): rd 8j,8j+4 -> 8j+1 (dead) | lev3 j(2,4 waves):
//   rd 16j+1,16j+9 -> 16j+2 (dead) | lev4(4 waves): rd 2,18 -> 32+c
//   root: rd 32,33 -> 2 (dead after lev4) | head reads row 2.
__global__ __launch_bounds__(NTH, 2) void formula_kernel(
    const int* __restrict__ pred_ids, const int* __restrict__ arg_ids,
    const int* __restrict__ op_ids,
    const float* __restrict__ b_pred, const float* __restrict__ b_bin,
    const float* __restrict__ b_final,
    const unsigned short* __restrict__ ws,
    float* __restrict__ out)
{
    __shared__ __align__(16) unsigned short s_ltab[6 * 100 * 64];  // 76800 B
    __shared__ __align__(16) unsigned short s_x[34][1024];         // 69632 B
    __shared__ __align__(16) unsigned short s_embop[100 * 64];     // 12800 B
    __shared__ unsigned char s_op[63 * 16 + 16];                   //  1024 B

    const int tid  = threadIdx.x;
    const int b0   = blockIdx.x * NB;
    const int lane = tid & 63;
    const int w    = tid >> 6;       // wave 0..7
    const int l15  = lane & 15;
    const int quad = lane >> 4;
    const int cg   = tid & 7;        // constant col-group (leaf phase)

    // ---- stage leaf tables into LDS (linear; 4800 short8 groups) ----
    for (int i = tid; i < 4800; i += NTH)
        *reinterpret_cast<short8*>(&s_ltab[i * 8]) = ld8s(ws + LTAB_OFF + i * 8);
    // ---- stage op embeddings (swizzled by r&7) ----
    for (int i = tid; i < 800; i += NTH) {
        int r = i >> 3, s = i & 7;
        *reinterpret_cast<short8*>(&s_embop[r * 64 + ((s ^ (r & 7)) << 3)]) =
            ld8s(ws + EMBO_OFF + r * 64 + s * 8);
    }
    for (int e = tid; e < 63 * 16; e += NTH) {
        int r = e >> 4, m = e & 15;
        s_op[r * 16 + m] = (unsigned char)op_ids[(b0 + m) * 63 + r];
    }

    // ---- persistent W_bin fragments: all 4 N-tiles in regs (24 VGPR) ----
    short8 wb_raw[3][2][4];
    #pragma unroll
    for (int p = 0; p < 3; ++p)
        #pragma unroll
        for (int h = 0; h < 2; ++h)
            #pragma unroll
            for (int nt = 0; nt < 4; ++nt)
                wb_raw[p][h][nt] = ld8s(ws + WBIN_OFF + (nt * 16 + l15) * 192
                                        + p * 64 + (quad + 4 * h) * 8);
    h8 (&wb)[3][2][4] = reinterpret_cast<h8(&)[3][2][4]>(wb_raw);

    float biasb[4];
    #pragma unroll
    for (int nt = 0; nt < 4; ++nt) {
        int n = nt * 16 + l15;
        biasb[nt] = (n < 50) ? b_bin[n] : 0.f;
    }
    h2 bias2[4];
    #pragma unroll
    for (int k = 0; k < 4; ++k) {
        int n0 = cg * 8 + 2 * k, n1 = n0 + 1;
        bias2[k] = (h2){(_Float16)((n0 < 50) ? b_pred[n0] : 0.f),
                        (_Float16)((n1 < 50) ? b_pred[n1] : 0.f)};
    }
    const h2 z2 = (h2){(_Float16)0.f, (_Float16)0.f};

    __syncthreads();

    for (int c = 0; c < 2; ++c) {
        // ---- leaf layer: 32 leaves x 16 m x 8 cg = 4096 jobs, 8/thread.
        //      ids from global (8-lane broadcast); tables from LDS ----
        #pragma unroll 4
        for (int p4 = 0; p4 < 8; ++p4) {
            int jj  = p4 * NTH + tid;          // 0..4095
            int lfl = jj >> 7;                 // 0..31
            int m   = (jj >> 3) & 15;
            int lf  = c * 32 + lfl;
            int pid = pred_ids[(b0 + m) * 64 + lf];
            const int* ap = arg_ids + (b0 + m) * 320 + lf * 5;
            int i1 = ap[0], i2 = ap[1], i3 = ap[2], i4 = ap[3], i5 = ap[4];
            h2 a0 = bias2[0], a1 = bias2[1], a2 = bias2[2], a3 = bias2[3];
            #define ACCT(ROW, P) {                                              \
                h8 t_ = ld8h(s_ltab + (P) * 6400 + (ROW) * 64 + cg * 8);        \
                const h2* tp_ = reinterpret_cast<const h2*>(&t_);               \
                a0 += tp_[0]; a1 += tp_[1]; a2 += tp_[2]; a3 += tp_[3]; }
            ACCT(pid, 0); ACCT(i1, 1); ACCT(i2, 2);
            ACCT(i3, 3); ACCT(i4, 4); ACCT(i5, 5);
            #undef ACCT
            a0 = __builtin_elementwise_max(a0, z2);
            a1 = __builtin_elementwise_max(a1, z2);
            a2 = __builtin_elementwise_max(a2, z2);
            a3 = __builtin_elementwise_max(a3, z2);
            union { h2 h[4]; short8 s; } u;
            u.h[0] = a0; u.h[1] = a1; u.h[2] = a2; u.h[3] = a3;
            *reinterpret_cast<short8*>(
                &s_x[lfl][m * 64 + ((cg ^ (m & 7)) << 3)]) = u.s;
        }
        __syncthreads();

        // ---- lev0: 16 nodes, 2/wave (in-place) ----
        #pragma unroll
        for (int i = 0; i < 2; ++i) {
            int j = w + 8 * i;
            TNODE(0, 4, 2 * j, 2 * j + 1, c * 16 + j, 2 * j);
        }
        __syncthreads();
        // ---- lev1: 8 nodes, 1/wave (in-place) ----
        { int j = w; TNODE(0, 4, 4 * j, 4 * j + 2, 32 + c * 8 + j, 4 * j); }
        __syncthreads();
        // ---- lev2: 4 nodes x 2 waves -> dead row 8j+1 ----
        {
            int j = w >> 1;
            if ((w & 1) == 0) TNODE(0, 2, 8 * j, 8 * j + 4, 48 + c * 4 + j, 8 * j + 1);
            else              TNODE(2, 2, 8 * j, 8 * j + 4, 48 + c * 4 + j, 8 * j + 1);
        }
        __syncthreads();
        // ---- lev3: 2 nodes x 4 waves -> dead row 16j+2 ----
        {
            int j = w >> 2;
            switch (w & 3) {
                case 0: TNODE(0, 1, 16 * j + 1, 16 * j + 9, 56 + c * 2 + j, 16 * j + 2); break;
                case 1: TNODE(1, 1, 16 * j + 1, 16 * j + 9, 56 + c * 2 + j, 16 * j + 2); break;
                case 2: TNODE(2, 1, 16 * j + 1, 16 * j + 9, 56 + c * 2 + j, 16 * j + 2); break;
                default: TNODE(3, 1, 16 * j + 1, 16 * j + 9, 56 + c * 2 + j, 16 * j + 2); break;
            }
        }
        __syncthreads();
        // ---- lev4 (subtree root, waves 0..3): rd 2,18 -> 32+c ----
        if (w < 4) {
            switch (w) {
                case 0: TNODE(0, 1, 2, 18, 60 + c, 32 + c); break;
                case 1: TNODE(1, 1, 2, 18, 60 + c, 32 + c); break;
                case 2: TNODE(2, 1, 2, 18, 60 + c, 32 + c); break;
                default: TNODE(3, 1, 2, 18, 60 + c, 32 + c); break;
            }
        }
        __syncthreads();
    }
    // ---- root (waves 0..3): rd 32,33 -> dead row 2 ----
    if (w < 4) {
        switch (w) {
            case 0: TNODE(0, 1, 32, 33, 62, 2); break;
            case 1: TNODE(1, 1, 32, 33, 62, 2); break;
            case 2: TNODE(2, 1, 32, 33, 62, 2); break;
            default: TNODE(3, 1, 32, 33, 62, 2); break;
        }
    }
    __syncthreads();

    // ---- final head via MFMA: 10 N-tiles over 8 waves (root = row 2) ----
    auto headtile = [&](int t) {
        f32x4 acc = {0.f, 0.f, 0.f, 0.f};
        int n2 = t * 16 + l15;
        const unsigned short* rroot = s_x[2];
        h8 x0 = ld8h(rroot + l15 * 64 + ((quad ^ (l15 & 7)) << 3));
        h8 x1 = ld8h(rroot + l15 * 64 + (((quad + 4) ^ (l15 & 7)) << 3));
        acc = mf(x0, ld8h(ws + WFIN_OFF + n2 * 64 + quad * 8), acc);
        acc = mf(x1, ld8h(ws + WFIN_OFF + n2 * 64 + (quad + 4) * 8), acc);
        if (n2 < 155) {
            float bias = b_final[n2];
            #pragma unroll
            for (int q = 0; q < 4; ++q) {
                int m = quad * 4 + q;
                out[(b0 + m) * 155 + n2] = acc[q] + bias;
            }
        }
    };
    headtile(w);
    if (w < 2) headtile(8 + w);
}

extern "C" void kernel_launch(void* const* d_in, const int* in_sizes, int n_in,
                              void* d_out, int out_size, void* d_ws, size_t ws_size,
                              hipStream_t stream) {
    const int*   pred_ids = (const int*)  d_in[0];
    const int*   arg_ids  = (const int*)  d_in[1];
    const int*   op_ids   = (const int*)  d_in[2];
    const float* emb_pred = (const float*)d_in[3];
    const float* emb_var  = (const float*)d_in[4];
    const float* emb_op   = (const float*)d_in[5];
    const float* W_pred   = (const float*)d_in[6];
    const float* b_pred   = (const float*)d_in[7];
    const float* W_bin    = (const float*)d_in[8];
    const float* b_bin    = (const float*)d_in[9];
    const float* W_final  = (const float*)d_in[10];
    const float* b_final  = (const float*)d_in[11];
    unsigned short* ws = (unsigned short*)d_ws;
    float* out = (float*)d_out;

    hipLaunchKernelGGL(prep_kernel, dim3(256), dim3(256), 0, stream,
                       emb_pred, emb_var, emb_op, W_pred, W_bin, W_final, ws);
    hipLaunchKernelGGL(formula_kernel, dim3(4096 / NB), dim3(NTH), 0, stream,
                       pred_ids, arg_ids, op_ids, b_pred, b_bin, b_final,
                       (const unsigned short*)ws, out);
}

// Round 17
// 36.399 us; speedup vs baseline: 9.6460x; 1.0690x over previous
//
#include <hip/hip_runtime.h>

using short8 = __attribute__((ext_vector_type(8))) short;
using h8     = __attribute__((ext_vector_type(8))) _Float16;
using h2     = __attribute__((ext_vector_type(2))) _Float16;
using f32x4  = __attribute__((ext_vector_type(4))) float;

#define NB  16
#define NTH 512
// ws layout (ushort units, all f16 bits)
#define WBIN_OFF 0         // [64 n][192 k]
#define WFIN_OFF 12288     // [160 n][64 k]
#define EMBO_OFF 22528     // [100 r][64 k]
#define LTAB_OFF 28928     // [6 p][100 v][64 n]
#define WS_USHORTS 67328

__device__ __forceinline__ unsigned short f2h_bits(float v) {
    _Float16 h = (_Float16)v;
    return *reinterpret_cast<unsigned short*>(&h);
}
__device__ __forceinline__ h8 ld8h(const unsigned short* p) {
    return *reinterpret_cast<const h8*>(p);
}
__device__ __forceinline__ short8 ld8s(const unsigned short* p) {
    return *reinterpret_cast<const short8*>(p);
}
__device__ __forceinline__ f32x4 mf(h8 a, h8 b, f32x4 c) {
    return __builtin_amdgcn_mfma_f32_16x16x32_f16(a, b, c, 0, 0, 0);
}

// ---------------- prep: build f16 weights + leaf lookup tables --------------
__global__ void prep_kernel(const float* __restrict__ emb_pred,
                            const float* __restrict__ emb_var,
                            const float* __restrict__ emb_op,
                            const float* __restrict__ W_pred,
                            const float* __restrict__ W_bin,
                            const float* __restrict__ W_final,
                            unsigned short* __restrict__ ws) {
    for (int i = blockIdx.x * blockDim.x + threadIdx.x; i < WS_USHORTS;
         i += gridDim.x * blockDim.x) {
        float v = 0.f;
        if (i < WFIN_OFF) {                      // W_bin [64][192]
            int n = i / 192, k = i - n * 192, p = k >> 6, j = k & 63;
            if (n < 50 && j < 50) v = W_bin[n * 150 + p * 50 + j];
        } else if (i < EMBO_OFF) {               // W_final [160][64]
            int t = i - WFIN_OFF, o = t >> 6, k = t & 63;
            if (o < 155 && k < 50) v = W_final[o * 50 + k];
        } else if (i < LTAB_OFF) {               // emb_op [100][64]
            int t = i - EMBO_OFF, r = t >> 6, j = t & 63;
            if (j < 50) v = emb_op[r * 50 + j];
        } else {                                 // leaf tables [6][100][64]
            int t = i - LTAB_OFF;
            int p = t / 6400, rest = t - p * 6400, vv = rest >> 6, n = rest & 63;
            if (n < 50) {
                const float* e = (p == 0) ? (emb_pred + vv * 50) : (emb_var + vv * 50);
                const float* wr = W_pred + n * 300 + p * 50;
                float acc = 0.f;
                for (int k = 0; k < 50; ++k) acc += e[k] * wr[k];
                v = acc;
            }
        }
        ws[i] = f2h_bits(v);
    }
}

// one tree node, compile-time N-tile subset [NT0, NT0+NTN)
#define TNODE(NT0, NTN, CL, CR, GN, DST) do {                                   \
    const unsigned short* rl_ = s_x[CL];                                        \
    const unsigned short* rr_ = s_x[CR];                                        \
    int r_ = s_op[(GN) * 16 + l15];                                             \
    h8 aL0 = ld8h(rl_ + l15 * 64 + ((quad ^ (l15 & 7)) << 3));                  \
    h8 aL1 = ld8h(rl_ + l15 * 64 + (((quad + 4) ^ (l15 & 7)) << 3));            \
    h8 aO0 = ld8h(s_embop + r_ * 64 + ((quad ^ (r_ & 7)) << 3));                \
    h8 aO1 = ld8h(s_embop + r_ * 64 + (((quad + 4) ^ (r_ & 7)) << 3));          \
    h8 aR0 = ld8h(rr_ + l15 * 64 + ((quad ^ (l15 & 7)) << 3));                  \
    h8 aR1 = ld8h(rr_ + l15 * 64 + (((quad + 4) ^ (l15 & 7)) << 3));            \
    f32x4 acc_[NTN];                                                            \
    _Pragma("unroll") for (int i_ = 0; i_ < (NTN); ++i_) {                      \
        acc_[i_] = (f32x4){0.f, 0.f, 0.f, 0.f};                                 \
        acc_[i_] = mf(aL0, wb[0][0][(NT0) + i_], acc_[i_]);                     \
        acc_[i_] = mf(aL1, wb[0][1][(NT0) + i_], acc_[i_]);                     \
        acc_[i_] = mf(aO0, wb[1][0][(NT0) + i_], acc_[i_]);                     \
        acc_[i_] = mf(aO1, wb[1][1][(NT0) + i_], acc_[i_]);                     \
        acc_[i_] = mf(aR0, wb[2][0][(NT0) + i_], acc_[i_]);                     \
        acc_[i_] = mf(aR1, wb[2][1][(NT0) + i_], acc_[i_]);                     \
    }                                                                           \
    unsigned short* drow_ = s_x[DST];                                           \
    _Pragma("unroll") for (int i_ = 0; i_ < (NTN); ++i_) {                      \
        int n_ = ((NT0) + i_) * 16 + l15;                                       \
        _Pragma("unroll") for (int q_ = 0; q_ < 4; ++q_) {                      \
            int m_ = quad * 4 + q_;                                             \
            float v_ = fmaxf(acc_[i_][q_] + biasb[(NT0) + i_], 0.f);            \
            drow_[m_ * 64 + (((n_ >> 3) ^ (m_ & 7)) << 3) + (n_ & 7)] = f2h_bits(v_); \
        }                                                                       \
    }                                                                           \
} while (0)

// ---------------- main fused kernel -----------------------------------------
// R10 structure verbatim (31.8 us best): 1 block = 16 batch, 8 waves, grid 256,
// whole tree / 7 barriers. ONE change: leaf loop is TABLE-MAJOR (2 groups x 8
// register-accumulated jobs; per group, all 8 gathers of table p issued
// together) so the L1 working set per phase is 1 table (12.8 KB), not 6
// (76.8 KB thrash) — R14 ablation: divergent leaf 19.4 us vs uniform 6.5 us.
__global__ __launch_bounds__(NTH, 2) void formula_kernel(
    const int* __restrict__ pred_ids, const int* __restrict__ arg_ids,
    const int* __restrict__ op_ids,
    const float* __restrict__ b_pred, const float* __restrict__ b_bin,
    const float* __restrict__ b_final,
    const unsigned short* __restrict__ ws,
    float* __restrict__ out)
{
    __shared__ __align__(16) unsigned short s_x[64][1024];         // 131072 B
    __shared__ __align__(16) unsigned short s_embop[100 * 64];     //  12800 B
    __shared__ __align__(8)  unsigned char  s_ids[64][16][8];      //   8192 B
    __shared__ unsigned char s_op[63 * 16 + 16];                   //   1024 B

    const int tid  = threadIdx.x;
    const int b0   = blockIdx.x * NB;
    const int lane = tid & 63;
    const int w    = tid >> 6;       // wave 0..7
    const int l15  = lane & 15;
    const int quad = lane >> 4;
    const int cg   = tid & 7;        // constant col-group (leaf phase)

    // ---- stage op embeddings (swizzled by r&7) ----
    for (int i = tid; i < 800; i += NTH) {
        int r = i >> 3, s = i & 7;
        *reinterpret_cast<short8*>(&s_embop[r * 64 + ((s ^ (r & 7)) << 3)]) =
            ld8s(ws + EMBO_OFF + r * 64 + s * 8);
    }
    // ---- stage ids: s_ids[leaf][m] = {pred, a0..a4, 0, 0} ----
    for (int e = tid; e < 64 * 16; e += NTH) {
        int m = e >> 6, lf = e & 63;
        unsigned char* rec = &s_ids[lf][m][0];
        rec[0] = (unsigned char)pred_ids[(b0 + m) * 64 + lf];
        #pragma unroll
        for (int a = 0; a < 5; ++a)
            rec[1 + a] = (unsigned char)arg_ids[(b0 + m) * 320 + lf * 5 + a];
        rec[6] = 0; rec[7] = 0;
    }
    for (int e = tid; e < 63 * 16; e += NTH) {
        int r = e >> 4, m = e & 15;
        s_op[r * 16 + m] = (unsigned char)op_ids[(b0 + m) * 63 + r];
    }

    // ---- persistent W_bin fragments: all 4 N-tiles in regs (24 VGPR) ----
    short8 wb_raw[3][2][4];
    #pragma unroll
    for (int p = 0; p < 3; ++p)
        #pragma unroll
        for (int h = 0; h < 2; ++h)
            #pragma unroll
            for (int nt = 0; nt < 4; ++nt)
                wb_raw[p][h][nt] = ld8s(ws + WBIN_OFF + (nt * 16 + l15) * 192
                                        + p * 64 + (quad + 4 * h) * 8);
    h8 (&wb)[3][2][4] = reinterpret_cast<h8(&)[3][2][4]>(wb_raw);

    float biasb[4];
    #pragma unroll
    for (int nt = 0; nt < 4; ++nt) {
        int n = nt * 16 + l15;
        biasb[nt] = (n < 50) ? b_bin[n] : 0.f;
    }
    h2 bias2[4];
    #pragma unroll
    for (int k = 0; k < 4; ++k) {
        int n0 = cg * 8 + 2 * k, n1 = n0 + 1;
        bias2[k] = (h2){(_Float16)((n0 < 50) ? b_pred[n0] : 0.f),
                        (_Float16)((n1 < 50) ? b_pred[n1] : 0.f)};
    }
    const h2 z2 = (h2){(_Float16)0.f, (_Float16)0.f};

    __syncthreads();

    // ---- leaf layer: 8192 jobs, 16/thread as 2 groups of 8, TABLE-MAJOR ----
    #pragma unroll 1
    for (int g8 = 0; g8 < 2; ++g8) {
        unsigned int ixv[8], iyv[8];
        #pragma unroll
        for (int q = 0; q < 8; ++q) {
            int jj = (g8 * 8 + q) * NTH + tid;
            int lf = jj >> 7, m = (jj >> 3) & 15;
            const unsigned int* ivp =
                reinterpret_cast<const unsigned int*>(&s_ids[lf][m][0]);
            ixv[q] = ivp[0]; iyv[q] = ivp[1];
        }
        h2 acc[8][4];
        #pragma unroll
        for (int q = 0; q < 8; ++q) {
            acc[q][0] = bias2[0]; acc[q][1] = bias2[1];
            acc[q][2] = bias2[2]; acc[q][3] = bias2[3];
        }
        // p-phases: all 8 gathers of one 12.8-KB table issued together
        #pragma unroll
        for (int p = 0; p < 6; ++p) {
            #pragma unroll
            for (int q = 0; q < 8; ++q) {
                int row = (p < 4) ? ((ixv[q] >> (8 * p)) & 255)
                                  : ((iyv[q] >> (8 * (p - 4))) & 255);
                h8 t_ = ld8h(ws + LTAB_OFF + p * 6400 + row * 64 + cg * 8);
                const h2* tp_ = reinterpret_cast<const h2*>(&t_);
                acc[q][0] += tp_[0]; acc[q][1] += tp_[1];
                acc[q][2] += tp_[2]; acc[q][3] += tp_[3];
            }
        }
        #pragma unroll
        for (int q = 0; q < 8; ++q) {
            int jj = (g8 * 8 + q) * NTH + tid;
            int lf = jj >> 7, m = (jj >> 3) & 15;
            union { h2 h[4]; short8 s; } u;
            u.h[0] = __builtin_elementwise_max(acc[q][0], z2);
            u.h[1] = __builtin_elementwise_max(acc[q][1], z2);
            u.h[2] = __builtin_elementwise_max(acc[q][2], z2);
            u.h[3] = __builtin_elementwise_max(acc[q][3], z2);
            *reinterpret_cast<short8*>(
                &s_x[lf][m * 64 + ((cg ^ (m & 7)) << 3)]) = u.s;
        }
    }
    __syncthreads();

    // ---- lev0: 32 nodes, 4 per wave (in-place; 1 wave/node) ----
    #pragma unroll
    for (int i = 0; i < 4; ++i) {
        int j = w + 8 * i;
        TNODE(0, 4, 2 * j, 2 * j + 1, j, 2 * j);
    }
    __syncthreads();
    // ---- lev1: 16 nodes, 2 per wave (in-place) ----
    #pragma unroll
    for (int i = 0; i < 2; ++i) {
        int j = w + 8 * i;
        TNODE(0, 4, 4 * j, 4 * j + 2, 32 + j, 4 * j);
    }
    __syncthreads();
    // ---- lev2: 8 nodes, 1 per wave (in-place) ----
    { int j = w; TNODE(0, 4, 8 * j, 8 * j + 4, 48 + j, 8 * j); }
    __syncthreads();
    // ---- lev3: 4 nodes x 2 waves -> dead row 16j+1 ----
    {
        int j = w >> 1;
        if ((w & 1) == 0) TNODE(0, 2, 16 * j, 16 * j + 8, 56 + j, 16 * j + 1);
        else              TNODE(2, 2, 16 * j, 16 * j + 8, 56 + j, 16 * j + 1);
    }
    __syncthreads();
    // ---- lev4: 2 nodes x 4 waves -> dead row 32j+2 ----
    {
        int j = w >> 2;
        switch (w & 3) {
            case 0: TNODE(0, 1, 32 * j + 1, 32 * j + 17, 60 + j, 32 * j + 2); break;
            case 1: TNODE(1, 1, 32 * j + 1, 32 * j + 17, 60 + j, 32 * j + 2); break;
            case 2: TNODE(2, 1, 32 * j + 1, 32 * j + 17, 60 + j, 32 * j + 2); break;
            default: TNODE(3, 1, 32 * j + 1, 32 * j + 17, 60 + j, 32 * j + 2); break;
        }
    }
    __syncthreads();
    // ---- lev5 (root, waves 0..3): reads rows 2,34 -> dead row 1 ----
    if (w < 4) {
        switch (w) {
            case 0: TNODE(0, 1, 2, 34, 62, 1); break;
            case 1: TNODE(1, 1, 2, 34, 62, 1); break;
            case 2: TNODE(2, 1, 2, 34, 62, 1); break;
            default: TNODE(3, 1, 2, 34, 62, 1); break;
        }
    }
    __syncthreads();

    // ---- final head via MFMA: 10 N-tiles over 8 waves (root = row 1) ----
    auto headtile = [&](int t) {
        f32x4 acc = {0.f, 0.f, 0.f, 0.f};
        int n2 = t * 16 + l15;
        const unsigned short* rroot = s_x[1];
        h8 x0 = ld8h(rroot + l15 * 64 + ((quad ^ (l15 & 7)) << 3));
        h8 x1 = ld8h(rroot + l15 * 64 + (((quad + 4) ^ (l15 & 7)) << 3));
        acc = mf(x0, ld8h(ws + WFIN_OFF + n2 * 64 + quad * 8), acc);
        acc = mf(x1, ld8h(ws + WFIN_OFF + n2 * 64 + (quad + 4) * 8), acc);
        if (n2 < 155) {
            float bias = b_final[n2];
            #pragma unroll
            for (int q = 0; q < 4; ++q) {
                int m = quad * 4 + q;
                out[(b0 + m) * 155 + n2] = acc[q] + bias;
            }
        }
    };
    headtile(w);
    if (w < 2) headtile(8 + w);
}

extern "C" void kernel_launch(void* const* d_in, const int* in_sizes, int n_in,
                              void* d_out, int out_size, void* d_ws, size_t ws_size,
                              hipStream_t stream) {
    const int*   pred_ids = (const int*)  d_in[0];
    const int*   arg_ids  = (const int*)  d_in[1];
    const int*   op_ids   = (const int*)  d_in[2];
    const float* emb_pred = (const float*)d_in[3];
    const float* emb_var  = (const float*)d_in[4];
    const float* emb_op   = (const float*)d_in[5];
    const float* W_pred   = (const float*)d_in[6];
    const float* b_pred   = (const float*)d_in[7];
    const float* W_bin    = (const float*)d_in[8];
    const float* b_bin    = (const float*)d_in[9];
    const float* W_final  = (const float*)d_in[10];
    const float* b_final  = (const float*)d_in[11];
    unsigned short* ws = (unsigned short*)d_ws;
    float* out = (float*)d_out;

    hipLaunchKernelGGL(prep_kernel, dim3(256), dim3(256), 0, stream,
                       emb_pred, emb_var, emb_op, W_pred, W_bin, W_final, ws);
    hipLaunchKernelGGL(formula_kernel, dim3(4096 / NB), dim3(NTH), 0, stream,
                       pred_ids, arg_ids, op_ids, b_pred, b_bin, b_final,
                       (const unsigned short*)ws, out);
}